// Round 2
// baseline (674.002 us; speedup 1.0000x reference)
//
#include <hip/hip_runtime.h>

#define XSTR 68  // padded stride for the transposed stats tile (16B-aligned, measured 0 conflicts)

// ---------------------------------------------------------------------------
// Symmetric-X 64x64 matmul in LDS: D = X^T * Y (== X*Y when X symmetric).
// Row-major [64][64] stride-64 buffers, 256 threads, 4x4 acc per thread.
// Trailing __syncthreads.
// ---------------------------------------------------------------------------
__device__ __forceinline__ void mm64(const float* X, const float* Y, float* D,
                                     int tid) {
  const int R = (tid >> 4) << 2;
  const int Cc = (tid & 15) << 2;
  float acc[4][4];
#pragma unroll
  for (int i = 0; i < 4; i++)
#pragma unroll
    for (int j = 0; j < 4; j++) acc[i][j] = 0.f;
#pragma unroll 4
  for (int kk = 0; kk < 64; kk++) {
    float4 a = *(const float4*)&X[(kk << 6) + R];
    float4 bb = *(const float4*)&Y[(kk << 6) + Cc];
    float av[4] = {a.x, a.y, a.z, a.w};
    float bv[4] = {bb.x, bb.y, bb.z, bb.w};
#pragma unroll
    for (int i = 0; i < 4; i++)
#pragma unroll
      for (int j = 0; j < 4; j++) acc[i][j] = fmaf(av[i], bv[j], acc[i][j]);
  }
#pragma unroll
  for (int i = 0; i < 4; i++) {
    *(float4*)&D[((R + i) << 6) + Cc] =
        make_float4(acc[i][0], acc[i][1], acc[i][2], acc[i][3]);
  }
  __syncthreads();
}

// ---------------------------------------------------------------------------
// Stage 1: partial second moments + rowsums per (b,k,pc) slice.
// grid 1024 = b(32) x k(4) x pc(8); block 128 = 2 waves.
// Wave-private transposed 64x64 tile; register prefetch of next chunk.
// Partial 64x64 written (non-atomically) to psum (= d_out scratch);
// rowsum partial to rsum (ws).
// ---------------------------------------------------------------------------
__global__ __launch_bounds__(128, 2) void k_stats(const float* __restrict__ x,
                                                  const int* __restrict__ idx,
                                                  float* __restrict__ psum,
                                                  float* __restrict__ rsum) {
  __shared__ __align__(16) float Xt[2][64 * XSTR];  // [px][ch] transposed
  __shared__ int chan[64];
  const int tid = threadIdx.x;
  const int wave = tid >> 6, lane = tid & 63;
  const int blk = blockIdx.x;
  const int b = blk >> 5;
  const int k = (blk >> 3) & 3;
  const int pcbase = (blk & 7) << 9;  // 512 pixels per block

  if (tid < 64) chan[tid] = idx[(tid << 2) + k];
  __syncthreads();

  const float* xb = x + ((size_t)b << 20);
  float* Xw = Xt[wave];
  const int R = lane & 56;         // acc rows (g)
  const int Cc = (lane & 7) << 3;  // acc cols (h)

  float acc[8][8];
#pragma unroll
  for (int i = 0; i < 8; i++)
#pragma unroll
    for (int j = 0; j < 8; j++) acc[i][j] = 0.f;
  float rs8[8];
#pragma unroll
  for (int i = 0; i < 8; i++) rs8[i] = 0.f;

  float v[64];
  {  // prefetch chunk 0
    const int p0 = pcbase + (wave << 6);
#pragma unroll
    for (int j = 0; j < 64; j++)
      v[j] = xb[((size_t)chan[j] << 12) + p0 + lane];
  }
  for (int c = 0; c < 4; c++) {
    // stage regs -> LDS (compiler inserts vmcnt wait)
#pragma unroll
    for (int j = 0; j < 16; j++)
      *(float4*)&Xw[lane * XSTR + (j << 2)] = make_float4(
          v[(j << 2)], v[(j << 2) + 1], v[(j << 2) + 2], v[(j << 2) + 3]);
    // prefetch next chunk while computing this one
    if (c < 3) {
      const int p0 = pcbase + ((((c + 1) << 1) + wave) << 6);
#pragma unroll
      for (int j = 0; j < 64; j++)
        v[j] = xb[((size_t)chan[j] << 12) + p0 + lane];
    }
#pragma unroll 2
    for (int kk = 0; kk < 64; kk++) {
      const float* row = &Xw[kk * XSTR];
      float4 a0 = *(const float4*)&row[R];
      float4 a1 = *(const float4*)&row[R + 4];
      float4 b0 = *(const float4*)&row[Cc];
      float4 b1 = *(const float4*)&row[Cc + 4];
      float av[8] = {a0.x, a0.y, a0.z, a0.w, a1.x, a1.y, a1.z, a1.w};
      float bv[8] = {b0.x, b0.y, b0.z, b0.w, b1.x, b1.y, b1.z, b1.w};
#pragma unroll
      for (int i = 0; i < 8; i++) {
        rs8[i] += av[i];
#pragma unroll
        for (int j = 0; j < 8; j++) acc[i][j] = fmaf(av[i], bv[j], acc[i][j]);
      }
    }
  }
  // in-block reduce: wave1 parks its acc in its (now dead) tile, wave0 sums
  if (wave == 1) {
#pragma unroll
    for (int i = 0; i < 8; i++) {
      *(float4*)&Xw[((R + i) << 6) + Cc] =
          make_float4(acc[i][0], acc[i][1], acc[i][2], acc[i][3]);
      *(float4*)&Xw[((R + i) << 6) + Cc + 4] =
          make_float4(acc[i][4], acc[i][5], acc[i][6], acc[i][7]);
    }
    if ((lane & 7) == 0) {
#pragma unroll
      for (int i = 0; i < 8; i++) Xw[4096 + R + i] = rs8[i];
    }
  }
  __syncthreads();
  if (wave == 0) {
    const float* X1 = Xt[1];
    float* pdst = psum + ((size_t)blk << 12);
#pragma unroll
    for (int i = 0; i < 8; i++) {
      float4 u0 = *(const float4*)&X1[((R + i) << 6) + Cc];
      float4 u1 = *(const float4*)&X1[((R + i) << 6) + Cc + 4];
      *(float4*)&pdst[((R + i) << 6) + Cc] =
          make_float4(acc[i][0] + u0.x, acc[i][1] + u0.y, acc[i][2] + u0.z,
                      acc[i][3] + u0.w);
      *(float4*)&pdst[((R + i) << 6) + Cc + 4] =
          make_float4(acc[i][4] + u1.x, acc[i][5] + u1.y, acc[i][6] + u1.z,
                      acc[i][7] + u1.w);
    }
    if ((lane & 7) == 0) {
#pragma unroll
      for (int i = 0; i < 8; i++)
        rsum[(blk << 6) + R + i] = rs8[i] + X1[4096 + R + i];
    }
  }
}

// ---------------------------------------------------------------------------
// Stage 2: reduce partials -> sigma, then Newton-Schulz (T=5) in LDS.
// One block per batch. Fused pass computes Ta=P^2 and Tb=P*SN together
// (shared A-fragment), then T3 = Ta * Tb = P^3*SN.
// ---------------------------------------------------------------------------
__global__ __launch_bounds__(256) void k_ns(const float* __restrict__ psum,
                                            const float* __restrict__ rsum,
                                            float* __restrict__ meanw,
                                            float* __restrict__ wmw) {
  __shared__ __align__(16) float SN[4096];
  __shared__ __align__(16) float Pm[4096];
  __shared__ __align__(16) float Ta[4096];
  __shared__ __align__(16) float Tb[4096];
  __shared__ float ml[64];
  __shared__ float tr_s;
  const int tid = threadIdx.x;
  const int b = blockIdx.x;

  if (tid < 64) {
    float s = 0.f;
#pragma unroll
    for (int p = 0; p < 32; p++) s += rsum[(((b << 5) + p) << 6) + tid];
    const float mu = s * (1.f / 16384.f);
    ml[tid] = mu;
    meanw[(b << 6) + tid] = mu;
  }
  // reduce 32 sigma partials (each thread owns 4 float4 slots)
  float4 a4[4];
#pragma unroll
  for (int i = 0; i < 4; i++) a4[i] = make_float4(0.f, 0.f, 0.f, 0.f);
  const float* pb = psum + ((size_t)(b << 5) << 12);
#pragma unroll 4
  for (int p = 0; p < 32; p++) {
#pragma unroll
    for (int i = 0; i < 4; i++) {
      float4 u = *(const float4*)&pb[(p << 12) + (((i << 8) + tid) << 2)];
      a4[i].x += u.x;
      a4[i].y += u.y;
      a4[i].z += u.z;
      a4[i].w += u.w;
    }
  }
  __syncthreads();  // ml ready
#pragma unroll
  for (int i = 0; i < 4; i++) {
    const int f = ((i << 8) + tid) << 2;  // base float index (mult of 4)
    const int g = f >> 6, c0 = f & 63;
    float4 r;
    r.x = a4[i].x * (1.f / 16384.f) - ml[g] * ml[c0];
    r.y = a4[i].y * (1.f / 16384.f) - ml[g] * ml[c0 + 1];
    r.z = a4[i].z * (1.f / 16384.f) - ml[g] * ml[c0 + 2];
    r.w = a4[i].w * (1.f / 16384.f) - ml[g] * ml[c0 + 3];
    *(float4*)&SN[f] = r;
  }
  __syncthreads();
  if (tid < 64) {  // trace via wave-0 shuffle reduce
    float d = SN[tid * 65];
#pragma unroll
    for (int off = 32; off; off >>= 1) d += __shfl_down(d, off);
    if (tid == 0) tr_s = 1.f / d;
  }
  __syncthreads();
  const float trinv = tr_s;
#pragma unroll
  for (int i = 0; i < 16; i++) {
    const int e = (i << 8) + tid;
    SN[e] *= trinv;
    Pm[e] = ((e >> 6) == (e & 63)) ? 1.f : 0.f;
  }
  __syncthreads();

  const int R4 = (tid >> 4) << 2, C4 = (tid & 15) << 2;
  for (int it = 0; it < 5; it++) {
    float p2[4][4], ps[4][4];
#pragma unroll
    for (int i = 0; i < 4; i++)
#pragma unroll
      for (int j = 0; j < 4; j++) {
        p2[i][j] = 0.f;
        ps[i][j] = 0.f;
      }
#pragma unroll 4
    for (int kk = 0; kk < 64; kk++) {
      float4 a = *(const float4*)&Pm[(kk << 6) + R4];
      float4 bp = *(const float4*)&Pm[(kk << 6) + C4];
      float4 bs = *(const float4*)&SN[(kk << 6) + C4];
      float av[4] = {a.x, a.y, a.z, a.w};
      float vp[4] = {bp.x, bp.y, bp.z, bp.w};
      float vs[4] = {bs.x, bs.y, bs.z, bs.w};
#pragma unroll
      for (int i = 0; i < 4; i++)
#pragma unroll
        for (int j = 0; j < 4; j++) {
          p2[i][j] = fmaf(av[i], vp[j], p2[i][j]);
          ps[i][j] = fmaf(av[i], vs[j], ps[i][j]);
        }
    }
#pragma unroll
    for (int i = 0; i < 4; i++) {
      *(float4*)&Ta[((R4 + i) << 6) + C4] =
          make_float4(p2[i][0], p2[i][1], p2[i][2], p2[i][3]);
      *(float4*)&Tb[((R4 + i) << 6) + C4] =
          make_float4(ps[i][0], ps[i][1], ps[i][2], ps[i][3]);
    }
    __syncthreads();
    float t3[4][4];
#pragma unroll
    for (int i = 0; i < 4; i++)
#pragma unroll
      for (int j = 0; j < 4; j++) t3[i][j] = 0.f;
#pragma unroll 4
    for (int kk = 0; kk < 64; kk++) {
      float4 a = *(const float4*)&Ta[(kk << 6) + R4];
      float4 bb = *(const float4*)&Tb[(kk << 6) + C4];
      float av[4] = {a.x, a.y, a.z, a.w};
      float bv[4] = {bb.x, bb.y, bb.z, bb.w};
#pragma unroll
      for (int i = 0; i < 4; i++)
#pragma unroll
        for (int j = 0; j < 4; j++) t3[i][j] = fmaf(av[i], bv[j], t3[i][j]);
    }
#pragma unroll
    for (int i = 0; i < 4; i++) {
      float4 p = *(const float4*)&Pm[((R4 + i) << 6) + C4];
      p.x = 1.5f * p.x - 0.5f * t3[i][0];
      p.y = 1.5f * p.y - 0.5f * t3[i][1];
      p.z = 1.5f * p.z - 0.5f * t3[i][2];
      p.w = 1.5f * p.w - 0.5f * t3[i][3];
      *(float4*)&Pm[((R4 + i) << 6) + C4] = p;
    }
    __syncthreads();
  }
  const float s = sqrtf(trinv);
#pragma unroll
  for (int i = 0; i < 16; i++) {
    const int e = (i << 8) + tid;
    wmw[(b << 12) + e] = Pm[e] * s;
  }
}

// ---------------------------------------------------------------------------
// Stage 3: per-block (redundant) batch sqrtvar + gamma + A=gamma@wm + ofs.
// Stores A TRANSPOSED (Amt[h*64+g]) so k_apply's LDS load is trivial.
// ---------------------------------------------------------------------------
__global__ __launch_bounds__(256) void k_gA(
    const float* __restrict__ wmw, const float* __restrict__ meanw,
    const float* __restrict__ eps1, const float* __restrict__ eps2,
    float* __restrict__ Amt, float* __restrict__ ofsw) {
  __shared__ __align__(16) float Wl[4096];
  __shared__ __align__(16) float Gm[4096];
  __shared__ __align__(16) float Al[4096];
  __shared__ __align__(16) float Sv[4096];
  __shared__ float ml[64], svm[64];
  const int tid = threadIdx.x;
  const int b = blockIdx.x;

  // sqrtvar over batch for all 4096 wm entries (ddof=1)
#pragma unroll 2
  for (int i = 0; i < 16; i++) {
    const int e = (i << 8) + tid;
    float v[32];
    float s = 0.f;
#pragma unroll
    for (int p = 0; p < 32; p++) {
      v[p] = wmw[(p << 12) + e];
      s += v[p];
    }
    const float mu = s * (1.f / 32.f);
    float s2 = 0.f;
#pragma unroll
    for (int p = 0; p < 32; p++) {
      const float d = v[p] - mu;
      s2 = fmaf(d, d, s2);
    }
    Sv[e] = sqrtf(s2 * (1.f / 31.f) + 1e-5f);
  }
  if (tid < 64) {
    ml[tid] = meanw[(b << 6) + tid];
    float v[32];
    float s = 0.f;
#pragma unroll
    for (int p = 0; p < 32; p++) {
      v[p] = meanw[(p << 6) + tid];
      s += v[p];
    }
    const float mu = s * (1.f / 32.f);
    float s2 = 0.f;
#pragma unroll
    for (int p = 0; p < 32; p++) {
      const float d = v[p] - mu;
      s2 = fmaf(d, d, s2);
    }
    svm[tid] = sqrtf(s2 * (1.f / 31.f) + 1e-5f);
  }
#pragma unroll
  for (int i = 0; i < 16; i++) {
    const int e = (i << 8) + tid;
    Wl[e] = wmw[(b << 12) + e];
  }
  __syncthreads();
#pragma unroll
  for (int i = 0; i < 16; i++) {
    const int e = (i << 8) + tid;
    const int g = e >> 6, h = e & 63;
    const int eu = (h >= g) ? e : ((h << 6) + g);  // mirror lower from upper
    Gm[e] = Wl[eu] + eps1[(b << 12) + eu] * Sv[eu];
  }
  __syncthreads();
  mm64(Gm, Wl, Al, tid);  // Al = gamma @ wm (Gm bitwise symmetric)
  // store transposed, coalesced global (LDS column reads are tiny here)
#pragma unroll
  for (int i = 0; i < 16; i++) {
    const int e = (i << 8) + tid;
    Amt[(b << 12) + e] = Al[((e & 63) << 6) + (e >> 6)];
  }
  if (tid < 64) {
    float dot = 0.f;
    for (int h = 0; h < 64; h++) dot = fmaf(Al[(tid << 6) + h], ml[h], dot);
    ofsw[(b << 6) + tid] = ml[tid] + eps2[(b << 6) + tid] * svm[tid] - dot;
  }
}

// ---------------------------------------------------------------------------
// Stage 4: out[b, idx[4g+k], p] = sum_h A[g,h]*x[b, idx[4h+k], p] + ofs[g].
// No X LDS tile: stream X rows straight from global into a double-buffered
// register file (8 h-steps per group). LDS holds only A^T (16 KiB).
// grid 1024 = b(32) x k(4) x pc(8); block 256 = 4 waves, 2 chunks each.
// ---------------------------------------------------------------------------
__global__ __launch_bounds__(256, 2) void k_apply(const float* __restrict__ x,
                                                  const int* __restrict__ idx,
                                                  const float* __restrict__ Amt,
                                                  const float* __restrict__ ofsw,
                                                  float* __restrict__ out) {
  __shared__ __align__(16) float AT[4096];  // AT[h*64+g] = A[g][h]
  __shared__ float ofsl[64];
  __shared__ int chan[64];
  const int tid = threadIdx.x;
  const int wave = tid >> 6, lane = tid & 63;
  const int blk = blockIdx.x;
  const int b = blk >> 5;
  const int k = (blk >> 3) & 3;
  const int pcbase = (blk & 7) << 9;

#pragma unroll
  for (int i = 0; i < 16; i++) {
    const int e = (i << 8) + tid;
    AT[e] = Amt[(b << 12) + e];
  }
  if (tid < 64) {
    ofsl[tid] = ofsw[(b << 6) + tid];
    chan[tid] = idx[(tid << 2) + k];
  }
  __syncthreads();

  const float* xb = x + ((size_t)b << 20);
  float* outb = out + ((size_t)b << 20);
  const int R = lane & 56;         // output g rows
  const int Cc = (lane & 7) << 3;  // pixel cols

  for (int c2 = 0; c2 < 2; c2++) {
    const int p0 = pcbase + (((c2 << 2) + wave) << 6);
    float acc[8][8];
#pragma unroll
    for (int i = 0; i < 8; i++) {
      const float o = ofsl[R + i];
#pragma unroll
      for (int j = 0; j < 8; j++) acc[i][j] = o;
    }
    float4 xv[2][16];
#pragma unroll
    for (int j = 0; j < 8; j++) {
      const float* p = &xb[((size_t)chan[j] << 12) + p0 + Cc];
      xv[0][2 * j] = *(const float4*)p;
      xv[0][2 * j + 1] = *(const float4*)(p + 4);
    }
#pragma unroll
    for (int hb = 0; hb < 8; hb++) {
      const int cur = hb & 1;
      if (hb < 7) {
#pragma unroll
        for (int j = 0; j < 8; j++) {
          const float* p =
              &xb[((size_t)chan[((hb + 1) << 3) + j] << 12) + p0 + Cc];
          xv[cur ^ 1][2 * j] = *(const float4*)p;
          xv[cur ^ 1][2 * j + 1] = *(const float4*)(p + 4);
        }
      }
#pragma unroll
      for (int j = 0; j < 8; j++) {
        const int h = (hb << 3) + j;
        float4 a0 = *(const float4*)&AT[(h << 6) + R];
        float4 a1 = *(const float4*)&AT[(h << 6) + R + 4];
        float av[8] = {a0.x, a0.y, a0.z, a0.w, a1.x, a1.y, a1.z, a1.w};
        float4 b0 = xv[cur][2 * j];
        float4 b1 = xv[cur][2 * j + 1];
        float bv[8] = {b0.x, b0.y, b0.z, b0.w, b1.x, b1.y, b1.z, b1.w};
#pragma unroll
        for (int i = 0; i < 8; i++)
#pragma unroll
          for (int jj = 0; jj < 8; jj++)
            acc[i][jj] = fmaf(av[i], bv[jj], acc[i][jj]);
      }
    }
#pragma unroll
    for (int i = 0; i < 8; i++) {
      float* dst = &outb[((size_t)chan[R + i] << 12) + p0 + Cc];
      *(float4*)dst = make_float4(acc[i][0], acc[i][1], acc[i][2], acc[i][3]);
      *(float4*)(dst + 4) =
          make_float4(acc[i][4], acc[i][5], acc[i][6], acc[i][7]);
    }
  }
}

// ---------------------------------------------------------------------------
// Workspace (floats): rsum@0 (65536) | meanw@65536 (2048) | wmw@67584 (131072)
//   | Amt@198656 (131072) | ofsw@329728 (2048)  -> 331776 floats = 1.33 MB.
// Sigma partials (1024 x 4096 = 16 MB) live in d_out (overwritten by k_apply).
// ---------------------------------------------------------------------------
extern "C" void kernel_launch(void* const* d_in, const int* in_sizes, int n_in,
                              void* d_out, int out_size, void* d_ws,
                              size_t ws_size, hipStream_t stream) {
  const float* x = (const float*)d_in[0];
  const int* idx = (const int*)d_in[1];
  const float* eps1 = (const float*)d_in[2];
  const float* eps2 = (const float*)d_in[3];
  float* out = (float*)d_out;
  float* ws = (float*)d_ws;

  float* psum = out;  // scratch: 1024*4096 floats, consumed before k_apply
  float* rsum = ws;
  float* meanw = ws + 65536;
  float* wmw = ws + 67584;
  float* Amt = ws + 198656;
  float* ofsw = ws + 329728;

  k_stats<<<1024, 128, 0, stream>>>(x, idx, psum, rsum);
  k_ns<<<32, 256, 0, stream>>>(psum, rsum, meanw, wmw);
  k_gA<<<32, 256, 0, stream>>>(wmw, meanw, eps1, eps2, Amt, ofsw);
  k_apply<<<1024, 256, 0, stream>>>(x, idx, Amt, ofsw, out);
}

// Round 3
// 401.229 us; speedup vs baseline: 1.6798x; 1.6798x over previous
//
#include <hip/hip_runtime.h>

typedef __attribute__((ext_vector_type(8))) short short8;
typedef __attribute__((ext_vector_type(4))) short short4v;
typedef __attribute__((ext_vector_type(4))) float f32x4;

#define MFMA16 __builtin_amdgcn_mfma_f32_16x16x32_bf16

// bf16 split by truncation: x = hi + lo exactly to ~2^-15 rel.
__device__ __forceinline__ short bf16t(float f) {
  return (short)(__float_as_uint(f) >> 16);
}
__device__ __forceinline__ float bf16f(short h) {
  return __uint_as_float(((unsigned)(unsigned short)h) << 16);
}

// ---------------------------------------------------------------------------
// Symmetric-X 64x64 fp32 matmul in LDS: D = X^T * Y (== X*Y, X symmetric).
// Row-major stride-64 buffers, 256 threads, 4x4 acc. Trailing barrier.
// ---------------------------------------------------------------------------
__device__ __forceinline__ void mm64(const float* X, const float* Y, float* D,
                                     int tid) {
  const int R = (tid >> 4) << 2;
  const int Cc = (tid & 15) << 2;
  float acc[4][4];
#pragma unroll
  for (int i = 0; i < 4; i++)
#pragma unroll
    for (int j = 0; j < 4; j++) acc[i][j] = 0.f;
#pragma unroll 4
  for (int kk = 0; kk < 64; kk++) {
    f32x4 a = *(const f32x4*)&X[(kk << 6) + R];
    f32x4 bb = *(const f32x4*)&Y[(kk << 6) + Cc];
#pragma unroll
    for (int i = 0; i < 4; i++)
#pragma unroll
      for (int j = 0; j < 4; j++) acc[i][j] = fmaf(a[i], bb[j], acc[i][j]);
  }
#pragma unroll
  for (int i = 0; i < 4; i++) {
    f32x4 r = {acc[i][0], acc[i][1], acc[i][2], acc[i][3]};
    *(f32x4*)&D[((R + i) << 6) + Cc] = r;
  }
  __syncthreads();
}

// ---------------------------------------------------------------------------
// Stage 1 (MFMA): partial sigma + rowsums per (b,k,pc) slice.
// grid 1024 = b(32) x k(4) x pc(8); block 128 = 2 waves; 37 KB LDS ->
// 4 blocks/CU (16 waves). Wave-private bf16 hi/lo tiles [ch64][px64] stride
// 72 (16B-aligned rows; frag reads land 8 dwords/bank = conflict-free).
// One frag load serves as both A(row g) and B(row h) operand of X*X^T.
// ---------------------------------------------------------------------------
__global__ __launch_bounds__(128, 2) void k_stats(const float* __restrict__ x,
                                                  const int* __restrict__ idx,
                                                  float* __restrict__ psum,
                                                  float* __restrict__ rsum_p) {
  __shared__ __align__(16) short Xt[2][2 * 64 * 72];  // per wave: hi | lo
  __shared__ int chan[64];
  __shared__ float rs_sh[64];
  const int tid = threadIdx.x;
  const int wave = tid >> 6, lane = tid & 63;
  const int q = lane >> 4, n15 = lane & 15;
  const int blk = blockIdx.x;
  const int b = blk >> 5, k = (blk >> 3) & 3, pc = blk & 7;

  if (tid < 64) {
    chan[tid] = idx[(tid << 2) + k];
    rs_sh[tid] = 0.f;
  }
  __syncthreads();

  const float* xb = x + ((size_t)b << 20);
  short* XH = &Xt[wave][0];
  short* XL = XH + 64 * 72;

  f32x4 acc[16];
#pragma unroll
  for (int t = 0; t < 16; t++) acc[t] = (f32x4){0.f, 0.f, 0.f, 0.f};
  float rsp[16];
#pragma unroll
  for (int i = 0; i < 16; i++) rsp[i] = 0.f;

  for (int c = 0; c < 4; c++) {
    const int p0 = (pc << 9) + (wave << 8) + (c << 6);
    // stage 64x64 fp32 -> bf16 hi/lo tiles; 1KB coalesced global loads
#pragma unroll
    for (int i = 0; i < 16; i++) {
      const int ch = (i << 2) + q;
      const f32x4 v =
          *(const f32x4*)&xb[((size_t)chan[ch] << 12) + p0 + (n15 << 2)];
      rsp[i] += v[0] + v[1] + v[2] + v[3];
      short4v hv, lv;
#pragma unroll
      for (int j = 0; j < 4; j++) {
        hv[j] = bf16t(v[j]);
        lv[j] = bf16t(v[j] - bf16f(hv[j]));
      }
      *(short4v*)&XH[ch * 72 + (n15 << 2)] = hv;
      *(short4v*)&XL[ch * 72 + (n15 << 2)] = lv;
    }
    // 2 K-steps of 32 px: 8 frag loads + 48 MFMAs (hi*hi + hi*lo + lo*hi)
#pragma unroll
    for (int s = 0; s < 2; s++) {
      const int pk = (s << 5) + (q << 3);
      short8 ah[4], al[4];
#pragma unroll
      for (int r = 0; r < 4; r++) {
        ah[r] = *(const short8*)&XH[((r << 4) + n15) * 72 + pk];
        al[r] = *(const short8*)&XL[((r << 4) + n15) * 72 + pk];
      }
#pragma unroll
      for (int gb = 0; gb < 4; gb++)
#pragma unroll
        for (int hb = 0; hb < 4; hb++) {
          const int t = (gb << 2) + hb;
          acc[t] = MFMA16(ah[gb], ah[hb], acc[t], 0, 0, 0);
          acc[t] = MFMA16(ah[gb], al[hb], acc[t], 0, 0, 0);
          acc[t] = MFMA16(al[gb], ah[hb], acc[t], 0, 0, 0);
        }
    }
  }
  // rowsums: reduce over the 16 lanes sharing q (px positions)
#pragma unroll
  for (int i = 0; i < 16; i++) {
    float r = rsp[i];
    r += __shfl_xor(r, 1);
    r += __shfl_xor(r, 2);
    r += __shfl_xor(r, 4);
    r += __shfl_xor(r, 8);
    if (n15 == 0) atomicAdd(&rs_sh[(i << 2) + q], r);
  }
  // park acc in own (dead) tile region: C/D map row=4q+reg, col=n15
  float* accsh = (float*)&Xt[wave][0];
#pragma unroll
  for (int gb = 0; gb < 4; gb++)
#pragma unroll
    for (int hb = 0; hb < 4; hb++) {
      const f32x4 a = acc[(gb << 2) + hb];
#pragma unroll
      for (int r = 0; r < 4; r++)
        accsh[(((gb << 4) + (q << 2) + r) << 6) + (hb << 4) + n15] = a[r];
    }
  __syncthreads();
  // cross-wave sum -> psum partial; rowsums -> rsum_p
  float* pdst = psum + ((size_t)blk << 12);
#pragma unroll
  for (int i = 0; i < 32; i++) {
    const int e = (i << 7) + tid;
    pdst[e] = ((const float*)&Xt[0][0])[e] + ((const float*)&Xt[1][0])[e];
  }
  if (tid < 64) rsum_p[(blk << 6) + tid] = rs_sh[tid];
}

// ---------------------------------------------------------------------------
// Stage 2: reduce 32 partials per batch -> sigw; rowsums -> meanw.
// grid 512 = b(32) x sub(16); fully parallel, coalesced.
// ---------------------------------------------------------------------------
__global__ __launch_bounds__(256) void k_red(const float* __restrict__ psum,
                                             const float* __restrict__ rsum_p,
                                             float* __restrict__ sigw,
                                             float* __restrict__ meanw) {
  const int tid = threadIdx.x;
  const int b = blockIdx.x >> 4, sub = blockIdx.x & 15;
  const int e = (sub << 8) + tid;
  float s = 0.f;
#pragma unroll
  for (int p = 0; p < 32; p++)
    s += psum[(((size_t)(b << 5) + p) << 12) + e];
  sigw[(b << 12) + e] = s;
  if (sub == 0 && tid < 64) {
    float r = 0.f;
#pragma unroll
    for (int p = 0; p < 32; p++) r += rsum_p[(((b << 5) + p) << 6) + tid];
    meanw[(b << 6) + tid] = r * (1.f / 16384.f);
  }
}

// ---------------------------------------------------------------------------
// Stage 3: sigma_N build + Newton-Schulz (T=5), fp32 in LDS. One block/batch.
// Fused pass: Ta = P^2 and Tb = P*SN share the A-fragment; then P^3*SN.
// ---------------------------------------------------------------------------
__global__ __launch_bounds__(256) void k_ns(const float* __restrict__ sigw,
                                            const float* __restrict__ meanw,
                                            float* __restrict__ wmw) {
  __shared__ __align__(16) float SN[4096];
  __shared__ __align__(16) float Pm[4096];
  __shared__ __align__(16) float Ta[4096];
  __shared__ __align__(16) float Tb[4096];
  __shared__ float ml[64];
  __shared__ float tr_s;
  const int tid = threadIdx.x;
  const int b = blockIdx.x;

  if (tid < 64) ml[tid] = meanw[(b << 6) + tid];
  __syncthreads();
#pragma unroll
  for (int i = 0; i < 16; i++) {
    const int e = (i << 8) + tid;
    const int g = e >> 6, h = e & 63;
    SN[e] = sigw[(b << 12) + e] * (1.f / 16384.f) - ml[g] * ml[h];
  }
  __syncthreads();
  if (tid < 64) {
    float d = SN[tid * 65];
#pragma unroll
    for (int off = 32; off; off >>= 1) d += __shfl_down(d, off);
    if (tid == 0) tr_s = 1.f / d;
  }
  __syncthreads();
  const float trinv = tr_s;
#pragma unroll
  for (int i = 0; i < 16; i++) {
    const int e = (i << 8) + tid;
    SN[e] *= trinv;
    Pm[e] = ((e >> 6) == (e & 63)) ? 1.f : 0.f;
  }
  __syncthreads();

  const int R4 = (tid >> 4) << 2, C4 = (tid & 15) << 2;
  for (int it = 0; it < 5; it++) {
    float p2[4][4], ps[4][4];
#pragma unroll
    for (int i = 0; i < 4; i++)
#pragma unroll
      for (int j = 0; j < 4; j++) {
        p2[i][j] = 0.f;
        ps[i][j] = 0.f;
      }
#pragma unroll 4
    for (int kk = 0; kk < 64; kk++) {
      f32x4 a = *(const f32x4*)&Pm[(kk << 6) + R4];
      f32x4 bp = *(const f32x4*)&Pm[(kk << 6) + C4];
      f32x4 bs = *(const f32x4*)&SN[(kk << 6) + C4];
#pragma unroll
      for (int i = 0; i < 4; i++)
#pragma unroll
        for (int j = 0; j < 4; j++) {
          p2[i][j] = fmaf(a[i], bp[j], p2[i][j]);
          ps[i][j] = fmaf(a[i], bs[j], ps[i][j]);
        }
    }
#pragma unroll
    for (int i = 0; i < 4; i++) {
      f32x4 r1 = {p2[i][0], p2[i][1], p2[i][2], p2[i][3]};
      f32x4 r2 = {ps[i][0], ps[i][1], ps[i][2], ps[i][3]};
      *(f32x4*)&Ta[((R4 + i) << 6) + C4] = r1;
      *(f32x4*)&Tb[((R4 + i) << 6) + C4] = r2;
    }
    __syncthreads();
    float t3[4][4];
#pragma unroll
    for (int i = 0; i < 4; i++)
#pragma unroll
      for (int j = 0; j < 4; j++) t3[i][j] = 0.f;
#pragma unroll 4
    for (int kk = 0; kk < 64; kk++) {
      f32x4 a = *(const f32x4*)&Ta[(kk << 6) + R4];
      f32x4 bb = *(const f32x4*)&Tb[(kk << 6) + C4];
#pragma unroll
      for (int i = 0; i < 4; i++)
#pragma unroll
        for (int j = 0; j < 4; j++) t3[i][j] = fmaf(a[i], bb[j], t3[i][j]);
    }
#pragma unroll
    for (int i = 0; i < 4; i++) {
      f32x4 p = *(const f32x4*)&Pm[((R4 + i) << 6) + C4];
#pragma unroll
      for (int j = 0; j < 4; j++) p[j] = 1.5f * p[j] - 0.5f * t3[i][j];
      *(f32x4*)&Pm[((R4 + i) << 6) + C4] = p;
    }
    __syncthreads();
  }
  const float s = sqrtf(trinv);
#pragma unroll
  for (int i = 0; i < 16; i++) {
    const int e = (i << 8) + tid;
    wmw[(b << 12) + e] = Pm[e] * s;
  }
}

// ---------------------------------------------------------------------------
// Stage 4: batch sqrtvar (ddof=1) of wm and mean, computed once.
// ---------------------------------------------------------------------------
__global__ __launch_bounds__(256) void k_var(const float* __restrict__ wmw,
                                             const float* __restrict__ meanw,
                                             float* __restrict__ svw,
                                             float* __restrict__ svm) {
  const int tid = threadIdx.x, blk = blockIdx.x;
  if (blk < 16) {
    const int e = (blk << 8) + tid;
    float v[32];
    float s = 0.f;
#pragma unroll
    for (int p = 0; p < 32; p++) {
      v[p] = wmw[(p << 12) + e];
      s += v[p];
    }
    const float mu = s * (1.f / 32.f);
    float s2 = 0.f;
#pragma unroll
    for (int p = 0; p < 32; p++) {
      const float d = v[p] - mu;
      s2 = fmaf(d, d, s2);
    }
    svw[e] = sqrtf(s2 * (1.f / 31.f) + 1e-5f);
  } else if (tid < 64) {
    float v[32];
    float s = 0.f;
#pragma unroll
    for (int p = 0; p < 32; p++) {
      v[p] = meanw[(p << 6) + tid];
      s += v[p];
    }
    const float mu = s * (1.f / 32.f);
    float s2 = 0.f;
#pragma unroll
    for (int p = 0; p < 32; p++) {
      const float d = v[p] - mu;
      s2 = fmaf(d, d, s2);
    }
    svm[tid] = sqrtf(s2 * (1.f / 31.f) + 1e-5f);
  }
}

// ---------------------------------------------------------------------------
// Stage 5: gamma = triu(wir)+triu(wir,1)^T; A = gamma@wm (fp32);
// ofs = mean + eps2*svm - A@mean; A exported as bf16 hi/lo pair.
// ---------------------------------------------------------------------------
__global__ __launch_bounds__(256) void k_gA(
    const float* __restrict__ wmw, const float* __restrict__ meanw,
    const float* __restrict__ eps1, const float* __restrict__ eps2,
    const float* __restrict__ svw, const float* __restrict__ svm,
    short* __restrict__ Ahl, float* __restrict__ ofsw) {
  __shared__ __align__(16) float Wl[4096];
  __shared__ __align__(16) float Gm[4096];
  __shared__ __align__(16) float Al[4096];
  __shared__ float ml[64];
  const int tid = threadIdx.x;
  const int b = blockIdx.x;
  if (tid < 64) ml[tid] = meanw[(b << 6) + tid];
#pragma unroll
  for (int i = 0; i < 16; i++) {
    const int e = (i << 8) + tid;
    Wl[e] = wmw[(b << 12) + e];
  }
  __syncthreads();
#pragma unroll
  for (int i = 0; i < 16; i++) {
    const int e = (i << 8) + tid;
    const int g = e >> 6, h = e & 63;
    const int eu = (h >= g) ? e : ((h << 6) + g);  // mirror lower from upper
    Gm[e] = Wl[eu] + eps1[(b << 12) + eu] * svw[eu];
  }
  __syncthreads();
  mm64(Gm, Wl, Al, tid);  // Al = gamma @ wm (Gm bitwise symmetric)
  short* Ab = Ahl + ((size_t)b << 13);
#pragma unroll
  for (int i = 0; i < 16; i++) {
    const int e = (i << 8) + tid;
    const float a = Al[e];
    const short h = bf16t(a);
    Ab[e] = h;
    Ab[4096 + e] = bf16t(a - bf16f(h));
  }
  if (tid < 64) {
    float dot = 0.f;
    for (int h = 0; h < 64; h++) dot = fmaf(Al[(tid << 6) + h], ml[h], dot);
    ofsw[(b << 6) + tid] = ml[tid] + eps2[(b << 6) + tid] * svm[tid] - dot;
  }
}

// ---------------------------------------------------------------------------
// Stage 6 (MFMA): out[b, idx[4g+k], p] = sum_h A[g,h] x[b, idx[4h+k], p] + ofs.
// A hi/lo bf16 in LDS (stride 72); X staged per-wave with the proven fp32
// transpose pattern [px][ch] stride 68, converted to bf16 hi/lo in-register
// during B-frag assembly. grid 1024 = b(32) x k(4) x pc(8); block 128.
// 53 KB LDS -> 3 blocks/CU. Stores are full 64B lines.
// ---------------------------------------------------------------------------
__global__ __launch_bounds__(128, 2) void k_apply(const float* __restrict__ x,
                                                  const int* __restrict__ idx,
                                                  const short* __restrict__ Ahl,
                                                  const float* __restrict__ ofsw,
                                                  float* __restrict__ out) {
  __shared__ __align__(16) short Ah[64 * 72];
  __shared__ __align__(16) short Alo[64 * 72];
  __shared__ __align__(16) float Xw2[2][64 * 68];
  __shared__ int chan[64];
  __shared__ float ofs_s[64];
  const int tid = threadIdx.x;
  const int wave = tid >> 6, lane = tid & 63;
  const int q = lane >> 4, n15 = lane & 15;
  const int blk = blockIdx.x;
  const int b = blk >> 5, k = (blk >> 3) & 3, pc = blk & 7;

  const short* Ag = Ahl + ((size_t)b << 13);
#pragma unroll
  for (int i = 0; i < 32; i++) {
    const int e = (i << 7) + tid;
    const int g = e >> 6, h = e & 63;
    Ah[g * 72 + h] = Ag[e];
    Alo[g * 72 + h] = Ag[4096 + e];
  }
  if (tid < 64) {
    chan[tid] = idx[(tid << 2) + k];
    ofs_s[tid] = ofsw[(b << 6) + tid];
  }
  __syncthreads();

  const float* xb = x + ((size_t)b << 20);
  float* outb = out + ((size_t)b << 20);
  float* XW = &Xw2[wave][0];

  for (int c = 0; c < 4; c++) {
    const int p0 = (pc << 9) + (wave << 8) + (c << 6);
    // transpose-stage X: gather 4 channels at px=lane, b128 LDS write
#pragma unroll
    for (int j = 0; j < 16; j++) {
      const int h4 = j << 2;
      f32x4 v;
      v[0] = xb[((size_t)chan[h4 + 0] << 12) + p0 + lane];
      v[1] = xb[((size_t)chan[h4 + 1] << 12) + p0 + lane];
      v[2] = xb[((size_t)chan[h4 + 2] << 12) + p0 + lane];
      v[3] = xb[((size_t)chan[h4 + 3] << 12) + p0 + lane];
      *(f32x4*)&XW[lane * 68 + h4] = v;
    }
    f32x4 acc[16];
#pragma unroll
    for (int gb = 0; gb < 4; gb++) {
#pragma unroll
      for (int nb = 0; nb < 4; nb++) {
        f32x4 o;
#pragma unroll
        for (int r = 0; r < 4; r++) o[r] = ofs_s[(gb << 4) + (q << 2) + r];
        acc[(gb << 2) + nb] = o;
      }
    }
#pragma unroll
    for (int s = 0; s < 2; s++) {
      const int hk = (s << 5) + (q << 3);
      short8 ah[4], al[4];
#pragma unroll
      for (int gb = 0; gb < 4; gb++) {
        ah[gb] = *(const short8*)&Ah[((gb << 4) + n15) * 72 + hk];
        al[gb] = *(const short8*)&Alo[((gb << 4) + n15) * 72 + hk];
      }
      short8 xh[4], xl[4];
#pragma unroll
      for (int nb = 0; nb < 4; nb++) {
        const float* src = &XW[((nb << 4) + n15) * 68 + hk];
        const f32x4 u0 = *(const f32x4*)src;
        const f32x4 u1 = *(const f32x4*)(src + 4);
        short8 hh, ll;
#pragma unroll
        for (int j = 0; j < 4; j++) {
          hh[j] = bf16t(u0[j]);
          ll[j] = bf16t(u0[j] - bf16f(hh[j]));
          hh[4 + j] = bf16t(u1[j]);
          ll[4 + j] = bf16t(u1[j] - bf16f(hh[4 + j]));
        }
        xh[nb] = hh;
        xl[nb] = ll;
      }
#pragma unroll
      for (int gb = 0; gb < 4; gb++)
#pragma unroll
        for (int nb = 0; nb < 4; nb++) {
          const int t = (gb << 2) + nb;
          acc[t] = MFMA16(ah[gb], xh[nb], acc[t], 0, 0, 0);
          acc[t] = MFMA16(ah[gb], xl[nb], acc[t], 0, 0, 0);
          acc[t] = MFMA16(al[gb], xh[nb], acc[t], 0, 0, 0);
        }
    }
    // store: full 64B lines per (q-group, nb)
#pragma unroll
    for (int gb = 0; gb < 4; gb++) {
#pragma unroll
      for (int r = 0; r < 4; r++) {
        const int g = (gb << 4) + (q << 2) + r;
        float* dst = &outb[((size_t)chan[g] << 12) + p0 + n15];
#pragma unroll
        for (int nb = 0; nb < 4; nb++) dst[nb << 4] = acc[(gb << 2) + nb][r];
      }
    }
  }
}

// ---------------------------------------------------------------------------
// Scratch: psum (1024x4096) + rsum_p (1024x64) live in d_out (consumed by
// k_red before k_apply overwrites). ws (floats):
//   sigw@0 (131072) | meanw@131072 (2048) | wmw@133120 (131072)
//   | svw@264192 (4096) | svm@268288 (64) | ofsw@268352 (2048)
//   | Ahl@270400 (131072 float-slots as short[262144])  -> ~1.61 MB
// ---------------------------------------------------------------------------
extern "C" void kernel_launch(void* const* d_in, const int* in_sizes, int n_in,
                              void* d_out, int out_size, void* d_ws,
                              size_t ws_size, hipStream_t stream) {
  const float* x = (const float*)d_in[0];
  const int* idx = (const int*)d_in[1];
  const float* eps1 = (const float*)d_in[2];
  const float* eps2 = (const float*)d_in[3];
  float* out = (float*)d_out;
  float* ws = (float*)d_ws;

  float* psum = out;                  // 1024*4096
  float* rsum_p = out + 4194304;      // 1024*64
  float* sigw = ws;
  float* meanw = ws + 131072;
  float* wmw = ws + 133120;
  float* svw = ws + 264192;
  float* svm = ws + 268288;
  float* ofsw = ws + 268352;
  short* Ahl = (short*)(ws + 270400);

  k_stats<<<1024, 128, 0, stream>>>(x, idx, psum, rsum_p);
  k_red<<<512, 256, 0, stream>>>(psum, rsum_p, sigw, meanw);
  k_ns<<<32, 256, 0, stream>>>(sigw, meanw, wmw);
  k_var<<<17, 256, 0, stream>>>(wmw, meanw, svw, svm);
  k_gA<<<32, 256, 0, stream>>>(wmw, meanw, eps1, eps2, svw, svm, Ahl, ofsw);
  k_apply<<<1024, 128, 0, stream>>>(x, idx, Ahl, ofsw, out);
}

// Round 4
// 311.988 us; speedup vs baseline: 2.1603x; 1.2860x over previous
//
#include <hip/hip_runtime.h>

typedef __attribute__((ext_vector_type(8))) short short8;
typedef __attribute__((ext_vector_type(4))) short short4v;
typedef __attribute__((ext_vector_type(4))) float f32x4;

#define MFMA16 __builtin_amdgcn_mfma_f32_16x16x32_bf16

// bf16 split by truncation: x = hi + lo (lo captures next 8 mantissa bits).
__device__ __forceinline__ short bf16t(float f) {
  return (short)(__float_as_uint(f) >> 16);
}
__device__ __forceinline__ float bf16f(short h) {
  return __uint_as_float(((unsigned)(unsigned short)h) << 16);
}

// ---------------------------------------------------------------------------
// Symmetric-X 64x64 fp32 matmul in LDS: D = X^T * Y (== X*Y, X symmetric).
// ---------------------------------------------------------------------------
__device__ __forceinline__ void mm64(const float* X, const float* Y, float* D,
                                     int tid) {
  const int R = (tid >> 4) << 2;
  const int Cc = (tid & 15) << 2;
  float acc[4][4];
#pragma unroll
  for (int i = 0; i < 4; i++)
#pragma unroll
    for (int j = 0; j < 4; j++) acc[i][j] = 0.f;
#pragma unroll 4
  for (int kk = 0; kk < 64; kk++) {
    f32x4 a = *(const f32x4*)&X[(kk << 6) + R];
    f32x4 bb = *(const f32x4*)&Y[(kk << 6) + Cc];
#pragma unroll
    for (int i = 0; i < 4; i++)
#pragma unroll
      for (int j = 0; j < 4; j++) acc[i][j] = fmaf(a[i], bb[j], acc[i][j]);
  }
#pragma unroll
  for (int i = 0; i < 4; i++) {
    f32x4 r = {acc[i][0], acc[i][1], acc[i][2], acc[i][3]};
    *(f32x4*)&D[((R + i) << 6) + Cc] = r;
  }
  __syncthreads();
}

// ---------------------------------------------------------------------------
// Stage 1 (MFMA): sigma second moments + rowsums, atomically accumulated.
// grid 1024 = b(32) x k(4) x pc(8); block 256 = 4 waves; wave w owns g-rows
// 16w..16w+15. Shared double-buffered bf16 hi/lo tile [ch64][px64] stride 72.
// 1 barrier per 64-px chunk; register prefetch of next chunk.
// ---------------------------------------------------------------------------
__global__ __launch_bounds__(256, 4) void k_stats(const float* __restrict__ x,
                                                  const int* __restrict__ idx,
                                                  float* __restrict__ sigw,
                                                  float* __restrict__ rsum) {
  __shared__ __align__(16) short XT[2][2 * 64 * 72];  // per buf: hi | lo
  __shared__ int chan[64];
  const int tid = threadIdx.x;
  const int w = tid >> 6, lane = tid & 63;
  const int q = lane >> 4, n15 = lane & 15;
  const int u = tid >> 4;     // 0..15 (channel sub-row)
  const int quad = tid & 15;  // px quad
  const int blk = blockIdx.x;
  const int b = blk >> 5, k = (blk >> 3) & 3, pc = blk & 7;

  if (tid < 64) chan[tid] = idx[(tid << 2) + k];
  __syncthreads();

  const float* xb = x + ((size_t)b << 20);
  const int pcbase = pc << 9;

  f32x4 acc[4];
#pragma unroll
  for (int t = 0; t < 4; t++) acc[t] = (f32x4){0.f, 0.f, 0.f, 0.f};
  float rsp[4] = {0.f, 0.f, 0.f, 0.f};

  f32x4 vv[4];
#pragma unroll
  for (int i = 0; i < 4; i++)  // prolog: chunk 0
    vv[i] = *(const f32x4*)&xb[((size_t)chan[(i << 4) + u] << 12) + pcbase +
                               (quad << 2)];

  for (int c = 0; c < 8; c++) {
    short* XH = &XT[c & 1][0];
    short* XL = XH + 64 * 72;
    // convert + stage into LDS; accumulate rowsums
#pragma unroll
    for (int i = 0; i < 4; i++) {
      const int ch = (i << 4) + u;
      rsp[i] += vv[i][0] + vv[i][1] + vv[i][2] + vv[i][3];
      short4v hv, lv;
#pragma unroll
      for (int j = 0; j < 4; j++) {
        hv[j] = bf16t(vv[i][j]);
        lv[j] = bf16t(vv[i][j] - bf16f(hv[j]));
      }
      *(short4v*)&XH[ch * 72 + (quad << 2)] = hv;
      *(short4v*)&XL[ch * 72 + (quad << 2)] = lv;
    }
    // prefetch next chunk
    if (c < 7) {
      const int p0 = pcbase + ((c + 1) << 6);
#pragma unroll
      for (int i = 0; i < 4; i++)
        vv[i] = *(const f32x4*)&xb[((size_t)chan[(i << 4) + u] << 12) + p0 +
                                   (quad << 2)];
    }
    __syncthreads();
    // compute: wave w rows (A) x all hb rows (B)
#pragma unroll
    for (int s = 0; s < 2; s++) {
      const int ko = (s << 5) + (q << 3);
      const short8 ah = *(const short8*)&XH[((w << 4) + n15) * 72 + ko];
      const short8 al = *(const short8*)&XL[((w << 4) + n15) * 72 + ko];
#pragma unroll
      for (int hb = 0; hb < 4; hb++) {
        const short8 bh = *(const short8*)&XH[((hb << 4) + n15) * 72 + ko];
        const short8 bl = *(const short8*)&XL[((hb << 4) + n15) * 72 + ko];
        acc[hb] = MFMA16(ah, bh, acc[hb], 0, 0, 0);
        acc[hb] = MFMA16(ah, bl, acc[hb], 0, 0, 0);
        acc[hb] = MFMA16(al, bh, acc[hb], 0, 0, 0);
      }
    }
  }
  // rowsums: reduce across the 16 quad-lanes (same u), one atomic per channel
#pragma unroll
  for (int i = 0; i < 4; i++) {
    float r = rsp[i];
    r += __shfl_xor(r, 1);
    r += __shfl_xor(r, 2);
    r += __shfl_xor(r, 4);
    r += __shfl_xor(r, 8);
    if (quad == 0) atomicAdd(&rsum[(b << 6) + (i << 4) + u], r);
  }
  // sigma: C-layout row m=4q+r -> g = 16w+4q+r; col n15 -> h = 16hb+n15
  float* sb = sigw + ((size_t)b << 12);
#pragma unroll
  for (int hb = 0; hb < 4; hb++)
#pragma unroll
    for (int r = 0; r < 4; r++)
      atomicAdd(&sb[(((w << 4) + (q << 2) + r) << 6) + (hb << 4) + n15],
                acc[hb][r]);
}

// ---------------------------------------------------------------------------
// Stage 2: mean + sigma_N build + Newton-Schulz (T=5), fp32 LDS. 1 block/batch.
// ---------------------------------------------------------------------------
__global__ __launch_bounds__(256) void k_ns(const float* __restrict__ sigw,
                                            const float* __restrict__ rsum,
                                            float* __restrict__ meanw,
                                            float* __restrict__ wmw) {
  __shared__ __align__(16) float SN[4096];
  __shared__ __align__(16) float Pm[4096];
  __shared__ __align__(16) float Ta[4096];
  __shared__ __align__(16) float Tb[4096];
  __shared__ float ml[64];
  __shared__ float tr_s;
  const int tid = threadIdx.x;
  const int b = blockIdx.x;

  if (tid < 64) {
    const float mu = rsum[(b << 6) + tid] * (1.f / 16384.f);
    ml[tid] = mu;
    meanw[(b << 6) + tid] = mu;
  }
  __syncthreads();
#pragma unroll
  for (int i = 0; i < 16; i++) {
    const int e = (i << 8) + tid;
    const int g = e >> 6, h = e & 63;
    SN[e] = sigw[(b << 12) + e] * (1.f / 16384.f) - ml[g] * ml[h];
  }
  __syncthreads();
  if (tid < 64) {
    float d = SN[tid * 65];
#pragma unroll
    for (int off = 32; off; off >>= 1) d += __shfl_down(d, off);
    if (tid == 0) tr_s = 1.f / d;
  }
  __syncthreads();
  const float trinv = tr_s;
#pragma unroll
  for (int i = 0; i < 16; i++) {
    const int e = (i << 8) + tid;
    SN[e] *= trinv;
    Pm[e] = ((e >> 6) == (e & 63)) ? 1.f : 0.f;
  }
  __syncthreads();

  const int R4 = (tid >> 4) << 2, C4 = (tid & 15) << 2;
  for (int it = 0; it < 5; it++) {
    float p2[4][4], ps[4][4];
#pragma unroll
    for (int i = 0; i < 4; i++)
#pragma unroll
      for (int j = 0; j < 4; j++) {
        p2[i][j] = 0.f;
        ps[i][j] = 0.f;
      }
#pragma unroll 4
    for (int kk = 0; kk < 64; kk++) {
      f32x4 a = *(const f32x4*)&Pm[(kk << 6) + R4];
      f32x4 bp = *(const f32x4*)&Pm[(kk << 6) + C4];
      f32x4 bs = *(const f32x4*)&SN[(kk << 6) + C4];
#pragma unroll
      for (int i = 0; i < 4; i++)
#pragma unroll
        for (int j = 0; j < 4; j++) {
          p2[i][j] = fmaf(a[i], bp[j], p2[i][j]);
          ps[i][j] = fmaf(a[i], bs[j], ps[i][j]);
        }
    }
#pragma unroll
    for (int i = 0; i < 4; i++) {
      f32x4 r1 = {p2[i][0], p2[i][1], p2[i][2], p2[i][3]};
      f32x4 r2 = {ps[i][0], ps[i][1], ps[i][2], ps[i][3]};
      *(f32x4*)&Ta[((R4 + i) << 6) + C4] = r1;
      *(f32x4*)&Tb[((R4 + i) << 6) + C4] = r2;
    }
    __syncthreads();
    float t3[4][4];
#pragma unroll
    for (int i = 0; i < 4; i++)
#pragma unroll
      for (int j = 0; j < 4; j++) t3[i][j] = 0.f;
#pragma unroll 4
    for (int kk = 0; kk < 64; kk++) {
      f32x4 a = *(const f32x4*)&Ta[(kk << 6) + R4];
      f32x4 bb = *(const f32x4*)&Tb[(kk << 6) + C4];
#pragma unroll
      for (int i = 0; i < 4; i++)
#pragma unroll
        for (int j = 0; j < 4; j++) t3[i][j] = fmaf(a[i], bb[j], t3[i][j]);
    }
#pragma unroll
    for (int i = 0; i < 4; i++) {
      f32x4 p = *(const f32x4*)&Pm[((R4 + i) << 6) + C4];
#pragma unroll
      for (int j = 0; j < 4; j++) p[j] = 1.5f * p[j] - 0.5f * t3[i][j];
      *(f32x4*)&Pm[((R4 + i) << 6) + C4] = p;
    }
    __syncthreads();
  }
  const float s = sqrtf(trinv);
#pragma unroll
  for (int i = 0; i < 16; i++) {
    const int e = (i << 8) + tid;
    wmw[(b << 12) + e] = Pm[e] * s;
  }
}

// ---------------------------------------------------------------------------
// Stage 3: batch sqrtvar (ddof=1) of wm and mean.
// ---------------------------------------------------------------------------
__global__ __launch_bounds__(256) void k_var(const float* __restrict__ wmw,
                                             const float* __restrict__ meanw,
                                             float* __restrict__ svw,
                                             float* __restrict__ svm) {
  const int tid = threadIdx.x, blk = blockIdx.x;
  if (blk < 16) {
    const int e = (blk << 8) + tid;
    float v[32];
    float s = 0.f;
#pragma unroll
    for (int p = 0; p < 32; p++) {
      v[p] = wmw[(p << 12) + e];
      s += v[p];
    }
    const float mu = s * (1.f / 32.f);
    float s2 = 0.f;
#pragma unroll
    for (int p = 0; p < 32; p++) {
      const float d = v[p] - mu;
      s2 = fmaf(d, d, s2);
    }
    svw[e] = sqrtf(s2 * (1.f / 31.f) + 1e-5f);
  } else if (tid < 64) {
    float v[32];
    float s = 0.f;
#pragma unroll
    for (int p = 0; p < 32; p++) {
      v[p] = meanw[(p << 6) + tid];
      s += v[p];
    }
    const float mu = s * (1.f / 32.f);
    float s2 = 0.f;
#pragma unroll
    for (int p = 0; p < 32; p++) {
      const float d = v[p] - mu;
      s2 = fmaf(d, d, s2);
    }
    svm[tid] = sqrtf(s2 * (1.f / 31.f) + 1e-5f);
  }
}

// ---------------------------------------------------------------------------
// Stage 4: gamma = triu(wir)+triu(wir,1)^T; A = gamma@wm (fp32);
// ofs = mean + eps2*svm - A@mean; A exported as bf16 hi/lo pair.
// ---------------------------------------------------------------------------
__global__ __launch_bounds__(256) void k_gA(
    const float* __restrict__ wmw, const float* __restrict__ meanw,
    const float* __restrict__ eps1, const float* __restrict__ eps2,
    const float* __restrict__ svw, const float* __restrict__ svm,
    short* __restrict__ Ahl, float* __restrict__ ofsw) {
  __shared__ __align__(16) float Wl[4096];
  __shared__ __align__(16) float Gm[4096];
  __shared__ __align__(16) float Al[4096];
  __shared__ float ml[64];
  const int tid = threadIdx.x;
  const int b = blockIdx.x;
  if (tid < 64) ml[tid] = meanw[(b << 6) + tid];
#pragma unroll
  for (int i = 0; i < 16; i++) {
    const int e = (i << 8) + tid;
    Wl[e] = wmw[(b << 12) + e];
  }
  __syncthreads();
#pragma unroll
  for (int i = 0; i < 16; i++) {
    const int e = (i << 8) + tid;
    const int g = e >> 6, h = e & 63;
    const int eu = (h >= g) ? e : ((h << 6) + g);  // mirror lower from upper
    Gm[e] = Wl[eu] + eps1[(b << 12) + eu] * svw[eu];
  }
  __syncthreads();
  mm64(Gm, Wl, Al, tid);  // Al = gamma @ wm (Gm bitwise symmetric)
  short* Ab = Ahl + ((size_t)b << 13);
#pragma unroll
  for (int i = 0; i < 16; i++) {
    const int e = (i << 8) + tid;
    const float a = Al[e];
    const short h = bf16t(a);
    Ab[e] = h;
    Ab[4096 + e] = bf16t(a - bf16f(h));
  }
  if (tid < 64) {
    float dot = 0.f;
    for (int h = 0; h < 64; h++) dot = fmaf(Al[(tid << 6) + h], ml[h], dot);
    ofsw[(b << 6) + tid] = ml[tid] + eps2[(b << 6) + tid] * svm[tid] - dot;
  }
}

// ---------------------------------------------------------------------------
// Stage 5 (MFMA): out[b, idx[4g+k], p] = sum_h A[g,h] x[b, idx[4h+k], p] + ofs.
// block 256 = 4 waves; wave w owns g-rows 16w..16w+15; A-frags loaded ONCE
// from global into registers. X staged transposed [px][ch] fp32 stride 68,
// double-buffered (2x17 KB), converted to bf16 hi/lo during frag assembly.
// grid 1024 = b(32) x k(4) x pc(8); 1 barrier per 64-px chunk.
// ---------------------------------------------------------------------------
__global__ __launch_bounds__(256, 4) void k_apply(const float* __restrict__ x,
                                                  const int* __restrict__ idx,
                                                  const short* __restrict__ Ahl,
                                                  const float* __restrict__ ofsw,
                                                  float* __restrict__ out) {
  __shared__ __align__(16) float XW[2][64 * 68];
  __shared__ int chan[64];
  const int tid = threadIdx.x;
  const int w = tid >> 6, lane = tid & 63;
  const int q = lane >> 4, n15 = lane & 15;
  const int blk = blockIdx.x;
  const int b = blk >> 5, k = (blk >> 3) & 3, pc = blk & 7;

  if (tid < 64) chan[tid] = idx[(tid << 2) + k];

  // A-fragments direct from global (lane n15 = A-row within gb=w)
  const short* Ab = Ahl + ((size_t)b << 13);
  short8 ah[2], al[2];
#pragma unroll
  for (int s = 0; s < 2; s++) {
    const int o = (((w << 4) + n15) << 6) + (s << 5) + (q << 3);
    ah[s] = *(const short8*)&Ab[o];
    al[s] = *(const short8*)&Ab[4096 + o];
  }
  const f32x4 of = *(const f32x4*)&ofsw[(b << 6) + (w << 4) + (q << 2)];
  __syncthreads();

  const float* xb = x + ((size_t)b << 20);
  float* outb = out + ((size_t)b << 20);
  const int pcbase = pc << 9;

  float v[16];
#pragma unroll
  for (int j = 0; j < 16; j++)  // prolog: chunk 0 (row chan[16w+j], px=lane)
    v[j] = xb[((size_t)chan[(w << 4) + j] << 12) + pcbase + lane];

  for (int c = 0; c < 8; c++) {
    float* XB = &XW[c & 1][0];
    // stage transposed: [px=lane][ch 16w..16w+15]
#pragma unroll
    for (int jj = 0; jj < 4; jj++) {
      f32x4 t = {v[(jj << 2)], v[(jj << 2) + 1], v[(jj << 2) + 2],
                 v[(jj << 2) + 3]};
      *(f32x4*)&XB[lane * 68 + (w << 4) + (jj << 2)] = t;
    }
    if (c < 7) {
      const int p0 = pcbase + ((c + 1) << 6);
#pragma unroll
      for (int j = 0; j < 16; j++)
        v[j] = xb[((size_t)chan[(w << 4) + j] << 12) + p0 + lane];
    }
    __syncthreads();

    const int p0 = pcbase + (c << 6);
    f32x4 acc[4];
#pragma unroll
    for (int nb = 0; nb < 4; nb++) acc[nb] = of;
#pragma unroll
    for (int s = 0; s < 2; s++) {
#pragma unroll
      for (int nb = 0; nb < 4; nb++) {
        const float* src = &XB[((nb << 4) + n15) * 68 + (s << 5) + (q << 3)];
        const f32x4 u0 = *(const f32x4*)src;
        const f32x4 u1 = *(const f32x4*)(src + 4);
        short8 xh, xl;
#pragma unroll
        for (int j = 0; j < 4; j++) {
          xh[j] = bf16t(u0[j]);
          xl[j] = bf16t(u0[j] - bf16f(xh[j]));
          xh[4 + j] = bf16t(u1[j]);
          xl[4 + j] = bf16t(u1[j] - bf16f(xh[4 + j]));
        }
        acc[nb] = MFMA16(ah[s], xh, acc[nb], 0, 0, 0);
        acc[nb] = MFMA16(ah[s], xl, acc[nb], 0, 0, 0);
        acc[nb] = MFMA16(al[s], xh, acc[nb], 0, 0, 0);
      }
    }
    // stores: per (r,nb) the wave covers 4 rows x 16 consecutive px (64B)
#pragma unroll
    for (int r = 0; r < 4; r++) {
      const int g = (w << 4) + (q << 2) + r;
      float* dst = &outb[((size_t)chan[g] << 12) + p0 + n15];
#pragma unroll
      for (int nb = 0; nb < 4; nb++) dst[nb << 4] = acc[nb][r];
    }
  }
}

// ---------------------------------------------------------------------------
// ws layout (floats): sigw@0 (131072, zeroed) | rsum@131072 (2048, zeroed)
//  | meanw@133120 (2048) | wmw@135168 (131072) | svw@266240 (4096)
//  | svm@270336 (64) | ofsw@270400 (2048) | Ahl@272448 (short[262144])
//  total 403520 floats = 1.614 MB (matches R0-proven footprint).
// ---------------------------------------------------------------------------
extern "C" void kernel_launch(void* const* d_in, const int* in_sizes, int n_in,
                              void* d_out, int out_size, void* d_ws,
                              size_t ws_size, hipStream_t stream) {
  const float* x = (const float*)d_in[0];
  const int* idx = (const int*)d_in[1];
  const float* eps1 = (const float*)d_in[2];
  const float* eps2 = (const float*)d_in[3];
  float* out = (float*)d_out;
  float* ws = (float*)d_ws;

  float* sigw = ws;
  float* rsum = ws + 131072;
  float* meanw = ws + 133120;
  float* wmw = ws + 135168;
  float* svw = ws + 266240;
  float* svm = ws + 270336;
  float* ofsw = ws + 270400;
  short* Ahl = (short*)(ws + 272448);

  hipMemsetAsync(ws, 0, (131072 + 2048) * sizeof(float), stream);
  k_stats<<<1024, 256, 0, stream>>>(x, idx, sigw, rsum);
  k_ns<<<32, 256, 0, stream>>>(sigw, rsum, meanw, wmw);
  k_var<<<17, 256, 0, stream>>>(wmw, meanw, svw, svm);
  k_gA<<<32, 256, 0, stream>>>(wmw, meanw, eps1, eps2, svw, svm, Ahl, ofsw);
  k_apply<<<1024, 256, 0, stream>>>(x, idx, Ahl, ofsw, out);
}